// Round 4
// baseline (347.838 us; speedup 1.0000x reference)
//
#include <hip/hip_runtime.h>
#include <math.h>

// Problem constants (B, N, D) = (256, 128, 128)
#define B_    256
#define N_    128
#define MAXP  30
#define OTHER_ 35      // D - 2*30 - 1 - 32
#define CIN1  131      // real channels into conv1 (row stride padded to 136)
#define NIDX  381      // 3*(N-1)

// wT layouts (kk-major): row r = kk*CINTOT + c, columns = COUT
#define CINTOT1 136
#define CINTOT2 256
#define CINTOT3 128
#define S_IDX  (B_ * NIDX)          // 97536
#define S_W1   (3 * CINTOT1 * 256)  // 104448
#define S_W2   (3 * CINTOT2 * 128)  // 98304
#define S_W3   (3 * CINTOT3 * 64)   // 24576

// ---------------------------------------------------------------------------
// Fused prep: idx convert (wave-uniform int64 detection) + 3 weight
// transposes into kk-major layout wT[kk*CINTOT + c][o], zero-padded rows.
// ---------------------------------------------------------------------------
__global__ __launch_bounds__(256) void prep_kernel(
    const void* __restrict__ rawIdx, int* __restrict__ idx32,
    const float* __restrict__ w1, float* __restrict__ wT1,
    const float* __restrict__ w2, float* __restrict__ wT2,
    const float* __restrict__ w3, float* __restrict__ wT3) {
  const int gid = blockIdx.x * 256 + threadIdx.x;
  if (gid < S_IDX) {
    // int64 LE view is (v,0,v,0,...) with v in [0,128)
    const int* r32 = (const int*)rawIdx;
    const int lane = threadIdx.x & 63;
    const int lo = r32[2 * lane];
    const int hi = r32[2 * lane + 1];
    const bool ok = (hi == 0 && lo >= 0 && lo < N_);
    const bool is64 = __all(ok);
    idx32[gid] = is64 ? (int)((const long long*)rawIdx)[gid] : r32[gid];
  } else if (gid < S_IDX + S_W1) {
    const int l = gid - S_IDX;
    const int o = l & 255, r = l >> 8;          // r in [0,408)
    const int kk = r / CINTOT1, c = r % CINTOT1;
    wT1[l] = (c < CIN1) ? w1[o * 393 + c * 3 + kk] : 0.f;
  } else if (gid < S_IDX + S_W1 + S_W2) {
    const int l = gid - (S_IDX + S_W1);
    const int o = l & 127, r = l >> 7;          // r in [0,768)
    const int kk = r >> 8, c = r & 255;
    wT2[l] = w2[o * 768 + c * 3 + kk];
  } else if (gid < S_IDX + S_W1 + S_W2 + S_W3) {
    const int l = gid - (S_IDX + S_W1 + S_W2);
    const int o = l & 63, r = l >> 6;           // r in [0,384)
    const int kk = r >> 7, c = r & 127;
    wT3[l] = w3[o * 384 + c * 3 + kk];
  }
}

// ---------------------------------------------------------------------------
// Embedding + collate (row stride 136, channels 131..135 zeroed).
// ---------------------------------------------------------------------------
__global__ __launch_bounds__(256) void embed_kernel(
    const float* __restrict__ feature,
    const float* __restrict__ col_embed,   // (200,32)
    const float* __restrict__ op_embed,    // (20,32)
    float* __restrict__ collate) {
  const int tid  = threadIdx.x;
  const int wave = tid >> 6;
  const int lane = tid & 63;
  const int b = blockIdx.x >> 5;
  const int n = ((blockIdx.x & 31) << 2) | wave;

  const float* fb = feature + ((size_t)b * 128) * 128 + n;  // stride 128 over d

  int civ = 0, oiv = 0;
  if (lane < MAXP) civ = (int)fb[(OTHER_ + lane) * 128];
  if (lane >= 32 && lane < 32 + MAXP) oiv = (int)fb[(OTHER_ + MAXP + (lane - 32)) * 128];
  const int L = (int)fb[95 * 128];  // wave-uniform

  const float* tp = (lane < 32) ? col_embed : op_embed;
  const int cl = lane & 31;
  float acc = 0.f;
  for (int i = 0; i < L; ++i) {
    const int cv = __shfl(civ, i);
    const int ov = __shfl(oiv, 32 + i);
    const int row = (lane < 32) ? cv : ov;
    acc += tp[row * 32 + cl];
  }

  float* out = collate + ((size_t)b * 128 + n) * CINTOT1;
  out[35 + lane] = acc;
  if (lane < 35) out[lane] = fb[lane * 128];
  if (lane < 32) out[99 + lane] = fb[(96 + lane) * 128];
  if (lane < 5)  out[131 + lane] = 0.f;   // pad channels
}

// ---------------------------------------------------------------------------
// Tree conv v4: wave-uniform weights.
// Block = (batch, chunk), 512 threads = 8 waves. chunk = (oc-chunk, j-chunk):
//   co = chunk / JCH  -> oc0 = co * (COUTtot/OCCH)   (OCW per block)
//   cj = chunk % JCH  -> jbase = cj * (128/JCH)
// Wave wv owns 8 consecutive oc (uniform via readfirstlane -> s_load weights).
// Lane owns nodes j = jbase + lane (+64 if JPT==2).
// Channels staged in NSTAGE sub-stages of CST into LDS (float4, no guards;
// CINSTRIDE = CST*NSTAGE). Input norm+leaky fused at staging. Stats partials
// per chunk in f64, combined in fixed order by the consumer.
// ---------------------------------------------------------------------------
template <int CINSTRIDE, int CST, int CINP, int CINTOT, int COUTtot,
          int OCCH, int JCH, int JPT, bool NORM_IN, int NCH_IN, int NSTAGE,
          int CREAL>
__global__ __launch_bounds__(512, 1) void conv_kernel(
    const float* __restrict__ X,        // (B,128,CINSTRIDE) node-major
    const int* __restrict__ idx,        // (B,381)
    const float* __restrict__ wT,       // (3*CINTOT, COUTtot) kk-major
    const float* __restrict__ bias,     // (COUTtot)
    const double* __restrict__ statsIn, // (B, NCH_IN, 2) partials
    float* __restrict__ Y,              // (B,128,COUTtot) node-major
    double* __restrict__ statsOut) {    // (B, OCCH*JCH, 2) partials
  __shared__ float xs[128 * CINP];
  __shared__ int nb_s[NIDX];
  __shared__ double red[16];

  const int b = blockIdx.x;
  const int chunk = blockIdx.y;
  const int co = chunk / JCH;
  const int cj = chunk - co * JCH;
  const int oc0 = co * (COUTtot / OCCH);
  const int jbase = cj * (128 / JCH);
  const int tid = threadIdx.x;
  const int wv = __builtin_amdgcn_readfirstlane(tid >> 6);  // uniform wave id
  const int lane = tid & 63;
  const int ocw = oc0 + wv * 8;        // wave's 8 output channels (uniform)

  float mean = 0.f, inv = 1.f;
  if (NORM_IN) {
    double S = 0.0, Q = 0.0;
#pragma unroll
    for (int i = 0; i < NCH_IN; ++i) {
      S += statsIn[(b * NCH_IN + i) * 2];
      Q += statsIn[(b * NCH_IN + i) * 2 + 1];
    }
    const double cnt = (double)CREAL * 128.0;
    const double m = S / cnt;
    double var = (Q - S * S / cnt) / (cnt - 1.0);
    if (var < 0.0) var = 0.0;
    mean = (float)m;
    inv = (float)(1.0 / (sqrt(var) + 1e-5));
  }

  float acc[8][JPT];
#pragma unroll
  for (int i = 0; i < 8; ++i)
#pragma unroll
    for (int jj = 0; jj < JPT; ++jj) acc[i][jj] = 0.f;

  const float* __restrict__ Xb = X + (size_t)b * (128 * CINSTRIDE);
  constexpr int F4PR = CST / 4;          // float4 per row per stage
  constexpr int NF4 = 128 * F4PR;

  int rowoff[JPT][3];
  double s_sum = 0.0, s_sq = 0.0;

  for (int s = 0; s < NSTAGE; ++s) {
    if (s > 0) __syncthreads();  // protect prior-stage reads
    for (int t = tid; t < NF4; t += 512) {
      const int n = t / F4PR;
      const int c4 = (t - n * F4PR) * 4;
      float4 v = *reinterpret_cast<const float4*>(&Xb[n * CINSTRIDE + s * CST + c4]);
      if (NORM_IN) {
        v.x = (v.x - mean) * inv; v.x = (v.x > 0.f) ? v.x : 0.01f * v.x;
        v.y = (v.y - mean) * inv; v.y = (v.y > 0.f) ? v.y : 0.01f * v.y;
        v.z = (v.z - mean) * inv; v.z = (v.z > 0.f) ? v.z : 0.01f * v.z;
        v.w = (v.w - mean) * inv; v.w = (v.w > 0.f) ? v.w : 0.01f * v.w;
      }
      *reinterpret_cast<float4*>(&xs[n * CINP + c4]) = v;
    }
    if (s == 0 && tid < NIDX) nb_s[tid] = idx[b * NIDX + tid];
    __syncthreads();

    if (s == 0) {
#pragma unroll
      for (int jj = 0; jj < JPT; ++jj) {
        const int j = jbase + lane + jj * 64;
#pragma unroll
        for (int kk = 0; kk < 3; ++kk) {
          const int nbv = (j > 0) ? nb_s[(j - 1) * 3 + kk] : 0;
          rowoff[jj][kk] = nbv * CINP;
        }
      }
    }

    // uniform weight row bases for this stage (scalar-load candidates)
    const float* __restrict__ wk0 = wT + ((size_t)(0 * CINTOT + s * CST)) * COUTtot + ocw;
    const float* __restrict__ wk1 = wT + ((size_t)(1 * CINTOT + s * CST)) * COUTtot + ocw;
    const float* __restrict__ wk2 = wT + ((size_t)(2 * CINTOT + s * CST)) * COUTtot + ocw;

    for (int c = 0; c < CST; c += 4) {
#pragma unroll
      for (int kk = 0; kk < 3; ++kk) {
        float xq[JPT][4];
#pragma unroll
        for (int jj = 0; jj < JPT; ++jj)
          *reinterpret_cast<float4*>(xq[jj]) =
              *reinterpret_cast<const float4*>(&xs[rowoff[jj][kk] + c]);
        const float* __restrict__ wr =
            (kk == 0 ? wk0 : kk == 1 ? wk1 : wk2) + c * COUTtot;
#pragma unroll
        for (int cc = 0; cc < 4; ++cc) {
          const float4 wa = *reinterpret_cast<const float4*>(wr + cc * COUTtot);
          const float4 wb = *reinterpret_cast<const float4*>(wr + cc * COUTtot + 4);
#pragma unroll
          for (int jj = 0; jj < JPT; ++jj) {
            const float xv = xq[jj][cc];
            acc[0][jj] = fmaf(wa.x, xv, acc[0][jj]);
            acc[1][jj] = fmaf(wa.y, xv, acc[1][jj]);
            acc[2][jj] = fmaf(wa.z, xv, acc[2][jj]);
            acc[3][jj] = fmaf(wa.w, xv, acc[3][jj]);
            acc[4][jj] = fmaf(wb.x, xv, acc[4][jj]);
            acc[5][jj] = fmaf(wb.y, xv, acc[5][jj]);
            acc[6][jj] = fmaf(wb.z, xv, acc[6][jj]);
            acc[7][jj] = fmaf(wb.w, xv, acc[7][jj]);
          }
        }
      }
    }
  }

  // ---- epilogue: bias, zero column, stats partial, store ----
  const float4 ba = *reinterpret_cast<const float4*>(bias + ocw);
  const float4 bb = *reinterpret_cast<const float4*>(bias + ocw + 4);
#pragma unroll
  for (int jj = 0; jj < JPT; ++jj) {
    const int j = jbase + lane + jj * 64;
    float4 oA, oB;
    if (j > 0) {
      oA.x = acc[0][jj] + ba.x; oA.y = acc[1][jj] + ba.y;
      oA.z = acc[2][jj] + ba.z; oA.w = acc[3][jj] + ba.w;
      oB.x = acc[4][jj] + bb.x; oB.y = acc[5][jj] + bb.y;
      oB.z = acc[6][jj] + bb.z; oB.w = acc[7][jj] + bb.w;
    } else {
      oA.x = oA.y = oA.z = oA.w = 0.f;
      oB.x = oB.y = oB.z = oB.w = 0.f;
    }
    s_sum += (double)oA.x + (double)oA.y + (double)oA.z + (double)oA.w +
             (double)oB.x + (double)oB.y + (double)oB.z + (double)oB.w;
    s_sq  += (double)oA.x * oA.x + (double)oA.y * oA.y +
             (double)oA.z * oA.z + (double)oA.w * oA.w +
             (double)oB.x * oB.x + (double)oB.y * oB.y +
             (double)oB.z * oB.z + (double)oB.w * oB.w;
    float* yp = Y + ((size_t)b * 128 + j) * COUTtot + ocw;
    *reinterpret_cast<float4*>(yp) = oA;
    *reinterpret_cast<float4*>(yp + 4) = oB;
  }

#pragma unroll
  for (int o = 32; o > 0; o >>= 1) {
    s_sum += __shfl_down(s_sum, o, 64);
    s_sq  += __shfl_down(s_sq, o, 64);
  }
  if (lane == 0) { red[wv * 2] = s_sum; red[wv * 2 + 1] = s_sq; }
  __syncthreads();
  if (tid == 0) {
    double S = 0.0, Q = 0.0;
#pragma unroll
    for (int i = 0; i < 8; ++i) { S += red[i * 2]; Q += red[i * 2 + 1]; }
    statsOut[(b * (OCCH * JCH) + chunk) * 2] = S;
    statsOut[(b * (OCCH * JCH) + chunk) * 2 + 1] = Q;
  }
}

// ---------------------------------------------------------------------------
// Final: combine conv3 stats partials, normalize, maxpool, 2-layer MLP.
// ---------------------------------------------------------------------------
__global__ __launch_bounds__(64) void final_kernel(
    const float* __restrict__ Y3,      // (B,128,64)
    const double* __restrict__ st,     // (B,2,2) partials
    const float* __restrict__ fw1,     // (32,64)
    const float* __restrict__ fb1,     // (32)
    const float* __restrict__ fw2,     // (1,32)
    const float* __restrict__ fb2,     // (1)
    float* __restrict__ out) {
  const int b = blockIdx.x;
  const int lane = threadIdx.x;

  const double S = st[(b * 2) * 2] + st[(b * 2 + 1) * 2];
  const double Q = st[(b * 2) * 2 + 1] + st[(b * 2 + 1) * 2 + 1];
  const double cnt = 64.0 * 128.0;
  const double m = S / cnt;
  double var = (Q - S * S / cnt) / (cnt - 1.0);
  if (var < 0.0) var = 0.0;
  const float mean = (float)m;
  const float inv = (float)(1.0 / (sqrt(var) + 1e-5));

  const float* Yb = Y3 + (size_t)b * 128 * 64;
  float mx = -3.4e38f;
  for (int n = 0; n < 128; ++n) {
    const float v = (Yb[n * 64 + lane] - mean) * inv;
    mx = fmaxf(mx, v);
  }
  __shared__ float pooled[64];
  __shared__ float hs[32];
  pooled[lane] = mx;
  __syncthreads();
  if (lane < 32) {
    float a = fb1[lane];
    for (int c = 0; c < 64; ++c) a = fmaf(pooled[c], fw1[lane * 64 + c], a);
    hs[lane] = fmaxf(a, 0.f);
  }
  __syncthreads();
  if (lane == 0) {
    float s = fb2[0];
    for (int t = 0; t < 32; ++t) s = fmaf(hs[t], fw2[t], s);
    out[b] = s;
  }
}

// ---------------------------------------------------------------------------
extern "C" void kernel_launch(void* const* d_in, const int* in_sizes, int n_in,
                              void* d_out, int out_size, void* d_ws, size_t ws_size,
                              hipStream_t stream) {
  const float* feature   = (const float*)d_in[0];
  const void*  indexes   = d_in[1];
  const float* col_embed = (const float*)d_in[2];
  const float* op_embed  = (const float*)d_in[3];
  const float* w1  = (const float*)d_in[4];
  const float* b1  = (const float*)d_in[5];
  const float* w2  = (const float*)d_in[6];
  const float* b2  = (const float*)d_in[7];
  const float* w3  = (const float*)d_in[8];
  const float* b3  = (const float*)d_in[9];
  const float* fw1 = (const float*)d_in[10];
  const float* fb1 = (const float*)d_in[11];
  const float* fw2 = (const float*)d_in[12];
  const float* fb2 = (const float*)d_in[13];
  float* out = (float*)d_out;

  char* ws = (char*)d_ws;
  size_t off = 0;
  auto carve = [&](size_t bytes) -> char* {
    off = (off + 255) & ~(size_t)255;
    char* p = ws + off;
    off += bytes;
    return p;
  };
  int*    idx32   = (int*)carve((size_t)S_IDX * sizeof(int));
  float*  wT1     = (float*)carve((size_t)S_W1 * sizeof(float));
  float*  wT2     = (float*)carve((size_t)S_W2 * sizeof(float));
  float*  wT3     = (float*)carve((size_t)S_W3 * sizeof(float));
  float*  collate = (float*)carve((size_t)B_ * 128 * CINTOT1 * sizeof(float));
  float*  Y1      = (float*)carve((size_t)B_ * 128 * 256 * sizeof(float));
  float*  Y2      = (float*)carve((size_t)B_ * 128 * 128 * sizeof(float));
  float*  Y3      = (float*)carve((size_t)B_ * 128 * 64 * sizeof(float));
  double* st1     = (double*)carve((size_t)B_ * 4 * 2 * sizeof(double));
  double* st2     = (double*)carve((size_t)B_ * 4 * 2 * sizeof(double));
  double* st3     = (double*)carve((size_t)B_ * 2 * 2 * sizeof(double));
  (void)ws_size; (void)in_sizes; (void)n_in; (void)out_size;

  constexpr int PREP_TOTAL = S_IDX + S_W1 + S_W2 + S_W3;
  hipLaunchKernelGGL(prep_kernel, dim3((PREP_TOTAL + 255) / 256), dim3(256), 0, stream,
                     indexes, idx32, w1, wT1, w2, wT2, w3, wT3);
  hipLaunchKernelGGL(embed_kernel, dim3(B_ * 32), dim3(256), 0, stream,
                     feature, col_embed, op_embed, collate);
  // conv1: stride 136, 2 stages of 68 (CINP 72), 4 oc-chunks, JPT 2
  hipLaunchKernelGGL((conv_kernel<136, 68, 72, CINTOT1, 256, 4, 1, 2, false, 1, 2, CIN1>),
                     dim3(B_, 4), dim3(512), 0, stream,
                     collate, idx32, wT1, b1, (const double*)nullptr, Y1, st1);
  // conv2: stride 256, 4 stages of 64 (CINP 68), 2 oc x 2 j chunks, JPT 1
  hipLaunchKernelGGL((conv_kernel<256, 64, 68, CINTOT2, 128, 2, 2, 1, true, 4, 4, 256>),
                     dim3(B_, 4), dim3(512), 0, stream,
                     Y1, idx32, wT2, b2, st1, Y2, st2);
  // conv3: stride 128, 2 stages of 64 (CINP 68), 2 j chunks, JPT 1
  hipLaunchKernelGGL((conv_kernel<128, 64, 68, CINTOT3, 64, 1, 2, 1, true, 4, 2, 128>),
                     dim3(B_, 2), dim3(512), 0, stream,
                     Y2, idx32, wT3, b3, st2, Y3, st3);
  hipLaunchKernelGGL(final_kernel, dim3(B_), dim3(64), 0, stream,
                     Y3, st3, fw1, fb1, fw2, fb2, out);
}